// Round 19
// baseline (265.076 us; speedup 1.0000x reference)
//
#include <hip/hip_runtime.h>
#include <hip/hip_bf16.h>

typedef __attribute__((ext_vector_type(8))) short short8;
typedef __attribute__((ext_vector_type(4))) float f32x4;

constexpr int cB = 4, cN = 8192, cC = 512, cH = 8, cD = 64;
constexpr int cM = cB * cN;        // 32768 tokens
constexpr int cHD = cH * cD;       // 512
constexpr int cBH = cB * cH;       // 32
constexpr float kEPS = 1e-6f;
constexpr int KV_SPLIT = 32;       // k45 split-K slices

// ---- RNE f32 -> bf16 (unbiased) ----
__device__ __forceinline__ ushort rne_bf16(float f) {
  unsigned u = __float_as_uint(f);
  u += 0x7fffu + ((u >> 16) & 1u);
  return (ushort)(u >> 16);
}
__device__ __forceinline__ float b2f(ushort u) {
  return __uint_as_float((unsigned)u << 16);
}

// ---------------- rounder: f32 -> single bf16 (RNE); used for Wqkv and x ----------------
__global__ __launch_bounds__(256) void round_w(const float* __restrict__ src,
    ushort* __restrict__ w, int n4) {
  int i = blockIdx.x * 256 + threadIdx.x;
  if (i >= n4) return;
  float4 v = reinterpret_cast<const float4*>(src)[i];
  ushort4 h;
  h.x = rne_bf16(v.x); h.y = rne_bf16(v.y);
  h.z = rne_bf16(v.z); h.w = rne_bf16(v.w);
  reinterpret_cast<ushort4*>(w)[i] = h;
}

// ---------------- single-bf16 MFMA GEMM: C = A[Mx512] @ W[NCx512]^T ----------------
// BARRIER-FREE K-loop via wave-PRIVATE staging: each wave stages its own
// 64 A-rows and 64 B-cols (8 KB private region) -> no inter-wave LDS sharing
// -> all sync is wave-local s_waitcnt (trivially race-free). Per K-step (BK=32):
//   vmcnt(0)            [own stage(kt) landed in own region]
//   ds_read 8 fragments [A 4x, B 4x short8]
//   lgkmcnt(0)          [values in regs -> overwrite safe]
//   STAGE(kt+1)         [8 gld_lds fly under MFMA; other waves hide latency]
//   16 MFMA
// A/B duplicated across wm/wn wave-pairs (2x L2 traffic, HBM unchanged).
// LDS 4 waves x 8 KB = 32 KB exact (colsum aliased) -> 5 blocks/CU.
// Swizzle (r11/r15-proven involution, wave-local rows): stage source unit
// u^=((lr>>1)&3), read unit lg^((r>>1)&3) -> 2-way banks (free).
// Bijective XCD swizzle + r14 ni-inner coalesced epilogue (r18-verified).
// EPI=0: qkv scatter as RNE-bf16 + fused qsum/ksum. EPI=1: out = acc + bias.
// NOTE (r7 lesson): gemm1 (the d_out writer) reads NOTHING from d_out.
template<int EPI, int NY>
__global__ __launch_bounds__(256) void gemm_mfma(
    const ushort* __restrict__ Ab, const ushort* __restrict__ Wb, int bstride,
    const float* __restrict__ bias,
    void* __restrict__ o0v, void* __restrict__ o1v, void* __restrict__ o2v,
    float* __restrict__ qsum, float* __restrict__ ksum) {
  constexpr int NT = cC / 32;                   // 16 K-steps of BK=32
  __shared__ ushort LDSu[4 * 4096];             // 4 waves x (A 2048 + B 2048) ushorts = 32 KB
  float* colsum = (float*)LDSu;                 // alive only after the K-loop
  const int t = threadIdx.x;
  const int wave = t >> 6, lane = t & 63;
  const int wm = wave >> 1, wn = wave & 1;      // 2x2 waves of 64x64
  const int l15 = lane & 15, lg = lane >> 4;

  // ---- XCD-chunked bijective swizzle (nwg % 8 == 0 for both launches) ----
  const int raw = blockIdx.y * gridDim.x + blockIdx.x;
  const int q8 = (int)(gridDim.x * NY) >> 3;
  const int wg2 = (raw & 7) * q8 + (raw >> 3);
  const int rowchunk = wg2 / NY, ycol = wg2 - rowchunk * NY;
  const int row0 = rowchunk * 128, col0 = ycol * 128;
  const size_t wofs = (size_t)(row0 >> 13) * (size_t)bstride;  // per-b B offset

  f32x4 acc[4][4] = {};

  const int srow = lane >> 2, sunit = lane & 3; // stage: 4 lanes x 16B per row
  const int agbase = row0 + wm * 64;            // this wave's global A-row base
  const int bgbase = col0 + wn * 64;            // this wave's global B-col base
  const ushort* Wp = Wb + wofs;
  ushort* Apriv = &LDSu[wave * 4096];           // 64 rows x 32 k
  ushort* Bpriv = &LDSu[wave * 4096 + 2048];

  // 4 calls x 1 KB: rows cc*16+srow, linear dest (lane*16B), swizzled source
#define STAGE_PRIV(basep, gbase, dstp, k0)                                      \
  _Pragma("unroll")                                                             \
  for (int cc = 0; cc < 4; ++cc) {                                              \
    const int lr = cc * 16 + srow;                                              \
    const int sw = sunit ^ ((lr >> 1) & 3);                                     \
    const size_t goff = (size_t)(gbase + lr) * cC + (k0) + sw * 8;              \
    __builtin_amdgcn_global_load_lds(                                           \
        (const __attribute__((address_space(1))) void*)(basep + goff),          \
        (__attribute__((address_space(3))) void*)(&dstp[cc * 512]),             \
        16, 0, 0);                                                              \
  }

  // ---- prologue: stage tile 0 into own region ----
  STAGE_PRIV(Ab, agbase, Apriv, 0);
  STAGE_PRIV(Wp, bgbase, Bpriv, 0);

  for (int kt = 0; kt < NT; ++kt) {
    // ---- own stage(kt) landed (wave-local; no barrier needed) ----
    asm volatile("s_waitcnt vmcnt(0)" ::: "memory");
    __builtin_amdgcn_sched_barrier(0);
    // ---- read fragments of own region into registers ----
    short8 ah[4], bhf[4];
    #pragma unroll
    for (int mi = 0; mi < 4; ++mi) {
      const int r = mi * 16 + l15;
      ah[mi] = *reinterpret_cast<const short8*>(
          &Apriv[r * 32 + (lg ^ ((r >> 1) & 3)) * 8]);
    }
    #pragma unroll
    for (int ni = 0; ni < 4; ++ni) {
      const int c = ni * 16 + l15;
      bhf[ni] = *reinterpret_cast<const short8*>(
          &Bpriv[c * 32 + (lg ^ ((c >> 1) & 3)) * 8]);
    }
    asm volatile("s_waitcnt lgkmcnt(0)" ::: "memory");
    __builtin_amdgcn_sched_barrier(0);
    // ---- overwrite own region with tile kt+1 (flies under MFMA) ----
    if (kt + 1 < NT) {
      STAGE_PRIV(Ab, agbase, Apriv, (kt + 1) * 32);
      STAGE_PRIV(Wp, bgbase, Bpriv, (kt + 1) * 32);
    }
    // ---- MFMA (register-only) ----
    #pragma unroll
    for (int ni = 0; ni < 4; ++ni)
      #pragma unroll
      for (int mi = 0; mi < 4; ++mi)
        acc[mi][ni] = __builtin_amdgcn_mfma_f32_16x16x32_bf16(ah[mi], bhf[ni], acc[mi][ni], 0, 0, 0);
  }
#undef STAGE_PRIV

  // ---- colsum init (aliases wave0's region; all waves past their loops join barrier) ----
  const bool qk_block = (EPI == 0) && (ycol < 8);
  if (qk_block) {
    __syncthreads();                            // all waves done with private LDS
    if (t < 128) colsum[t] = 0.f;
    __syncthreads();
  }

  // ---- epilogue: C/D map col=lane&15, row=(lane>>4)*4+r; ni-inner stores ----
  float csum[4] = {};
  #pragma unroll
  for (int mi = 0; mi < 4; ++mi) {
    #pragma unroll
    for (int r = 0; r < 4; ++r) {
      const int m = row0 + wm * 64 + mi * 16 + lg * 4 + r;
      #pragma unroll
      for (int ni = 0; ni < 4; ++ni) {
        const int col = col0 + wn * 64 + ni * 16 + l15;
        const float val = acc[mi][ni][r];
        if (EPI == 0) {
          const int which = col >> 9;
          const int c2 = col & 511;
          const int h = c2 >> 6, d = c2 & 63;
          const int bb = m >> 13, n = m & 8191;
          const size_t idx = (((size_t)(bb * cH + h)) * cN + n) * cD + d;
          if (which < 2) {
            const float sv = 1.f / (1.f + __expf(-val));
            if (which == 0) ((ushort*)o0v)[idx] = rne_bf16(sv);
            else            ((ushort*)o1v)[idx] = rne_bf16(sv);
            csum[ni] += sv;
          } else {
            ((ushort*)o2v)[idx] = rne_bf16(val * 0.125f);
          }
        } else {
          ((float*)o0v)[(size_t)m * cC + col] = val + bias[col];
        }
      }
    }
  }
  if (qk_block) {
    #pragma unroll
    for (int ni = 0; ni < 4; ++ni)
      atomicAdd(&colsum[wn * 64 + ni * 16 + l15], csum[ni]);
    __syncthreads();
    if (t < 128) {
      const int col = col0 + t;
      const int c2 = col & 511;
      const int h = c2 >> 6, d = c2 & 63;
      const int bb = row0 >> 13;
      float* tgt = (col < 512) ? qsum : ksum;
      atomicAdd(&tgt[(bb * cH + h) * cD + d], colsum[t]);
    }
  }
}

// ---------------- K34: si, so; accumulate Sq, Sk (bf16 q/k inputs) ----------------
__global__ __launch_bounds__(256) void k34_flow(const ushort* __restrict__ q,
      const ushort* __restrict__ k, const float* __restrict__ qsum,
      const float* __restrict__ ksum, float* __restrict__ si,
      float* __restrict__ Sq, float* __restrict__ Sk) {
  const int bh = blockIdx.x;
  const int n0 = blockIdx.y * 256;
  const int t = threadIdx.x;
  const int wave = t >> 6, lane = t & 63;
  const int g = lane >> 4, j = lane & 15;
  const ushort* qb = q + (size_t)bh * cN * cD;
  const ushort* kb = k + (size_t)bh * cN * cD;
  const float4 ks4 = *(const float4*)&ksum[bh * 64 + j * 4];
  const float4 qs4 = *(const float4*)&qsum[bh * 64 + j * 4];
  const float ksd[4] = {ks4.x + kEPS, ks4.y + kEPS, ks4.z + kEPS, ks4.w + kEPS};
  const float qsd[4] = {qs4.x + kEPS, qs4.y + kEPS, qs4.z + kEPS, qs4.w + kEPS};
  float aSq[4] = {}, aSk[4] = {};
  for (int i = 0; i < 16; ++i) {
    const int n = n0 + wave * 64 + i * 4 + g;
    const ushort4 qu = *(const ushort4*)&qb[(size_t)n * cD + j * 4];
    const ushort4 ku = *(const ushort4*)&kb[(size_t)n * cD + j * 4];
    const float qa[4] = {b2f(qu.x), b2f(qu.y), b2f(qu.z), b2f(qu.w)};
    const float ka[4] = {b2f(ku.x), b2f(ku.y), b2f(ku.z), b2f(ku.w)};
    float t1 = 0.f, t2 = 0.f;
    #pragma unroll
    for (int c = 0; c < 4; ++c) {
      t1 = fmaf(qa[c] + kEPS, ksd[c], t1);
      t2 = fmaf(ka[c] + kEPS, qsd[c], t2);
    }
    #pragma unroll
    for (int off = 1; off < 16; off <<= 1) {
      t1 += __shfl_xor(t1, off);
      t2 += __shfl_xor(t2, off);
    }
    const float si_n = 1.f / (t1 + kEPS);
    const float so_n = 1.f / (t2 + kEPS);
    if (j == 0) si[(size_t)bh * cN + n] = si_n;
    #pragma unroll
    for (int c = 0; c < 4; ++c) {
      aSq[c] = fmaf(qa[c], si_n, aSq[c]);
      aSk[c] = fmaf(ka[c], so_n, aSk[c]);
    }
  }
  #pragma unroll
  for (int c = 0; c < 4; ++c) {
    aSq[c] += __shfl_xor(aSq[c], 16); aSq[c] += __shfl_xor(aSq[c], 32);
    aSk[c] += __shfl_xor(aSk[c], 16); aSk[c] += __shfl_xor(aSk[c], 32);
  }
  __shared__ float sAq[4][64], sAk[4][64];
  if (g == 0) {
    #pragma unroll
    for (int c = 0; c < 4; ++c) { sAq[wave][j * 4 + c] = aSq[c]; sAk[wave][j * 4 + c] = aSk[c]; }
  }
  __syncthreads();
  if (t < 64) {
    atomicAdd(&Sq[bh * 64 + t], sAq[0][t] + sAq[1][t] + sAq[2][t] + sAq[3][t]);
    atomicAdd(&Sk[bh * 64 + t], sAk[0][t] + sAk[1][t] + sAk[2][t] + sAk[3][t]);
  }
}

// ---------------- K45: split-K kv partials (NO atomics), ev inline; bf16 k/v in ----------------
__global__ __launch_bounds__(256) void k45_kv(const ushort* __restrict__ kk_,
      const ushort* __restrict__ vv, const float* __restrict__ Sq,
      float* __restrict__ kvpart, float* __restrict__ zpart) {
  const int bh = blockIdx.x;
  const int y = blockIdx.y;                       // KV_SPLIT slices
  constexpr int ROWS = cN / KV_SPLIT;             // 256
  const int n0 = y * ROWS;
  const int t = threadIdx.x;
  const int d = t & 63, eb = t >> 6;
  const int g = t >> 4, j = t & 15;               // 16 ev-groups of 16 lanes
  const int sr = t >> 4, sc = (t & 15) * 4;       // stage mapping
  const ushort* kb = kk_ + (size_t)bh * cN * cD;
  const ushort* vb = vv + (size_t)bh * cN * cD;
  const float4 sq4 = *(const float4*)&Sq[bh * 64 + j * 4];
  const float SqE[4] = {sq4.x + kEPS, sq4.y + kEPS, sq4.z + kEPS, sq4.w + kEPS};
  __shared__ float ks[32][64];
  __shared__ float vs[32][64];
  __shared__ float evs[32];
  __shared__ float zl[16];
  float acc[16] = {};
  float zacc = 0.f;
  ushort4 pk0 = *(const ushort4*)&kb[(size_t)(n0 + sr) * cD + sc];
  ushort4 pk1 = *(const ushort4*)&kb[(size_t)(n0 + 16 + sr) * cD + sc];
  ushort4 pv0 = *(const ushort4*)&vb[(size_t)(n0 + sr) * cD + sc];
  ushort4 pv1 = *(const ushort4*)&vb[(size_t)(n0 + 16 + sr) * cD + sc];
  for (int c0 = 0; c0 < ROWS; c0 += 32) {
    __syncthreads();
    *(float4*)&ks[sr][sc]      = make_float4(b2f(pk0.x), b2f(pk0.y), b2f(pk0.z), b2f(pk0.w));
    *(float4*)&ks[sr + 16][sc] = make_float4(b2f(pk1.x), b2f(pk1.y), b2f(pk1.z), b2f(pk1.w));
    *(float4*)&vs[sr][sc]      = make_float4(b2f(pv0.x), b2f(pv0.y), b2f(pv0.z), b2f(pv0.w));
    *(float4*)&vs[sr + 16][sc] = make_float4(b2f(pv1.x), b2f(pv1.y), b2f(pv1.z), b2f(pv1.w));
    __syncthreads();
    if (c0 + 32 < ROWS) {
      pk0 = *(const ushort4*)&kb[(size_t)(n0 + c0 + 32 + sr) * cD + sc];
      pk1 = *(const ushort4*)&kb[(size_t)(n0 + c0 + 48 + sr) * cD + sc];
      pv0 = *(const ushort4*)&vb[(size_t)(n0 + c0 + 32 + sr) * cD + sc];
      pv1 = *(const ushort4*)&vb[(size_t)(n0 + c0 + 48 + sr) * cD + sc];
    }
    #pragma unroll
    for (int rr = 0; rr < 2; ++rr) {
      const int r = g * 2 + rr;
      const float4 kk4 = *(const float4*)&ks[r][j * 4];
      float tt = 0.f;
      tt = fmaf(kk4.x + kEPS, SqE[0], tt);
      tt = fmaf(kk4.y + kEPS, SqE[1], tt);
      tt = fmaf(kk4.z + kEPS, SqE[2], tt);
      tt = fmaf(kk4.w + kEPS, SqE[3], tt);
      #pragma unroll
      for (int off = 1; off < 16; off <<= 1) tt += __shfl_xor(tt, off);
      if (j == 0) {
        const float cs = fminf(fmaxf(tt + kEPS, -1.f), 1.f);
        const float e = __expf(cs);
        evs[r] = e;
        zacc += e;
      }
    }
    __syncthreads();
    #pragma unroll
    for (int r = 0; r < 32; ++r) {
      const float kd = ks[r][d] * evs[r];
      #pragma unroll
      for (int j2 = 0; j2 < 16; ++j2)
        acc[j2] = fmaf(kd, vs[r][eb * 16 + j2], acc[j2]);
    }
  }
  if (j == 0) zl[g] = zacc;
  __syncthreads();
  if (t == 0) {
    float z = 0.f;
    #pragma unroll
    for (int i = 0; i < 16; ++i) z += zl[i];
    zpart[y * cBH + bh] = z;
  }
  float* kvb = kvpart + ((size_t)y * cBH + bh) * 4096 + d * 64 + eb * 16;
  #pragma unroll
  for (int j2 = 0; j2 < 16; ++j2) kvb[j2] = acc[j2];
}

// ---------------- K5R: fold split-K partials -> kvm, Zb (deterministic) ----------------
__global__ __launch_bounds__(256) void k5r_reduce(const float* __restrict__ kvpart,
      const float* __restrict__ zpart, float* __restrict__ kvm, float* __restrict__ Zb) {
  const int bh = blockIdx.x;
  const int yq = blockIdx.y;                      // 4 chunks of 1024
  const int t = threadIdx.x;
  for (int i = yq * 1024 + t; i < (yq + 1) * 1024; i += 256) {
    float s = 0.f;
    #pragma unroll
    for (int yy = 0; yy < KV_SPLIT; ++yy)
      s += kvpart[((size_t)yy * cBH + bh) * 4096 + i];
    kvm[(size_t)bh * 4096 + i] = s;
  }
  if (yq == 0 && t == 0) {
    float z = 0.f;
    #pragma unroll
    for (int yy = 0; yy < KV_SPLIT; ++yy) z += zpart[yy * cBH + bh];
    Zb[bh] = z;
  }
}

// ---------------- KVW: kvw[b][c*512 + h*64+d] = RNE( (N/Z)·(kv_bh @ Wproj_h^T)[d,c] ) ----------------
__global__ __launch_bounds__(256) void kvw_build(const float* __restrict__ kvm,
      const float* __restrict__ Wproj, const float* __restrict__ Zb,
      ushort* __restrict__ kvw) {
  const int bh = blockIdx.x;                     // 32
  const int c0 = blockIdx.y * 128;               // 4 c-chunks
  const int b = bh >> 3, h = bh & 7;
  const int t = threadIdx.x;
  __shared__ float kvs[64][64];
  for (int i = t; i < 4096; i += 256)
    kvs[i >> 6][i & 63] = kvm[(size_t)bh * 4096 + i];
  __syncthreads();
  const float zs = (float)cN / Zb[bh];
  const int cl = t & 127, half = t >> 7;         // c-local, d-half
  const int c = c0 + cl;
  float acc[32] = {};
  for (int ec = 0; ec < 64; ec += 8) {
    float w[8];
    #pragma unroll
    for (int e = 0; e < 8; ++e)
      w[e] = Wproj[(size_t)c * cHD + h * 64 + ec + e];
    #pragma unroll
    for (int d = 0; d < 32; ++d)
      #pragma unroll
      for (int e = 0; e < 8; ++e)
        acc[d] = fmaf(kvs[half * 32 + d][ec + e], w[e], acc[d]);
  }
  ushort* dst = kvw + (size_t)b * cC * cHD + (size_t)c * cC + h * 64 + half * 32;
  #pragma unroll
  for (int d = 0; d < 32; ++d) dst[d] = rne_bf16(acc[d] * zs);
}

// ---------------- K6c: A' = RNE_bf16( q · si · sa ), [M][512] token-major; bf16 q in ----------------
__global__ __launch_bounds__(256) void k6c_scaleq(const ushort* __restrict__ q,
      const float* __restrict__ si, const float* __restrict__ Sk,
      ushort* __restrict__ xq) {
  const int bh = blockIdx.x;
  const int b = bh >> 3, head = bh & 7;
  const int n0 = blockIdx.y * 256;
  const int t = threadIdx.x;
  const int wave = t >> 6, lane = t & 63;
  const int g = lane >> 4, j = lane & 15;
  const ushort* qb = q + (size_t)bh * cN * cD;
  const float4 sk4 = *(const float4*)&Sk[bh * 64 + j * 4];
  const float SkE[4] = {sk4.x + kEPS, sk4.y + kEPS, sk4.z + kEPS, sk4.w + kEPS};
  for (int i = 0; i < 16; ++i) {
    const int n = n0 + wave * 64 + i * 4 + g;
    const ushort4 qu = *(const ushort4*)&qb[(size_t)n * cD + j * 4];
    const float q0 = b2f(qu.x), q1 = b2f(qu.y), q2 = b2f(qu.z), q3 = b2f(qu.w);
    float t2 = 0.f;
    t2 = fmaf(q0 + kEPS, SkE[0], t2);
    t2 = fmaf(q1 + kEPS, SkE[1], t2);
    t2 = fmaf(q2 + kEPS, SkE[2], t2);
    t2 = fmaf(q3 + kEPS, SkE[3], t2);
    #pragma unroll
    for (int off = 1; off < 16; off <<= 1) t2 += __shfl_xor(t2, off);
    const float sa_n = 1.f / (1.f + __expf(-(t2 + kEPS)));
    const float s = si[(size_t)bh * cN + n] * sa_n;
    ushort4 hh;
    hh.x = rne_bf16(q0 * s);
    hh.y = rne_bf16(q1 * s);
    hh.z = rne_bf16(q2 * s);
    hh.w = rne_bf16(q3 * s);
    const size_t m = (size_t)b * cN + n;
    *(ushort4*)&xq[m * cC + head * 64 + j * 4] = hh;
  }
}

extern "C" void kernel_launch(void* const* d_in, const int* in_sizes, int n_in,
                              void* d_out, int out_size, void* d_ws, size_t ws_size,
                              hipStream_t stream) {
  (void)in_sizes; (void)n_in; (void)out_size;
  const float* x     = (const float*)d_in[0];
  const float* Wqkv  = (const float*)d_in[1];
  const float* Wproj = (const float*)d_in[2];
  const float* bproj = (const float*)d_in[3];
  float* out = (float*)d_out;
  float* ws  = (float*)d_ws;

  const size_t SLAB = (size_t)cBH * cN * cD;       // 16,777,216 elements
  const size_t OFF_Q   = 0;                        // q bf16
  const size_t OFF_K   = SLAB;                     // k bf16
  const size_t OFF_V   = 2 * SLAB;                 // v bf16 [first half]; xq [second half]
  const size_t OFF_ACC = 3 * SLAB;
  const size_t ACC_FLOATS = 2048 * 4 + 32 + (size_t)cBH * cD * cD;  // 139,296
  const size_t OFF_R   = OFF_ACC + ACC_FLOATS;     // time-shared region
  const size_t R_FLOATS = (size_t)3 * cHD * cC;    // 786,432 floats (r8-proven fit)
  const size_t TOTAL   = OFF_R + R_FLOATS;
  if (ws_size < TOTAL * sizeof(float)) return;

  ushort* q16 = (ushort*)(ws + OFF_Q);             // SLAB ushorts = 32 MB
  ushort* k16 = (ushort*)(ws + OFF_K);
  ushort* v16 = (ushort*)(ws + OFF_V);
  ushort* xq  = (ushort*)(ws + OFF_V + SLAB / 2);  // disjoint second half of v region
  float* ksum = ws + OFF_ACC;
  float* qsum = ksum + 2048;
  float* Sk   = ksum + 4096;
  float* Sq   = ksum + 6144;
  float* Zb   = ksum + 8192;
  float* kvm  = ksum + 8224;

  // region R timeline (786,432 floats):
  //   [0 .. 393216)         wq bf16 (786,432 ushorts)    alive: round_w -> gemm0
  //   [0 .. 262144)         si                            alive: k34 -> k6c (after gemm0)
  //   [262144 .. 786432)    kvw bf16 (1,048,576 ushorts)  alive: kvw_build -> gemm1
  ushort* wq  = (ushort*)(ws + OFF_R);
  float*  si  = ws + OFF_R;
  ushort* kvw = (ushort*)(ws + OFF_R + (size_t)cBH * cN);   // +262144 floats

  // d_out scratch timeline (gemm1 writes ALL of d_out last, reads none of it):
  //   xs bf16 [0 .. 8M floats)       alive: round_w(x) -> gemm0
  //   kvpart  [8M .. 12M floats)     alive: k45 -> k5r
  //   zpart   [12M .. 12M+1K)        alive: k45 -> k5r
  ushort* xs    = (ushort*)out;                          // 16M ushorts = 32 MB
  float* kvpart = out + (size_t)8 * 1024 * 1024;
  float* zpart  = kvpart + (size_t)KV_SPLIT * cBH * 4096;

  hipMemsetAsync(ksum, 0, ACC_FLOATS * sizeof(float), stream);

  round_w<<<(3 * cHD * cC / 4 + 255) / 256, 256, 0, stream>>>(Wqkv, wq, 3 * cHD * cC / 4);
  round_w<<<((size_t)cM * cC / 4 + 255) / 256, 256, 0, stream>>>(x, xs, cM * cC / 4);
  gemm_mfma<0, 12><<<dim3(cM / 128, (3 * cHD) / 128), 256, 0, stream>>>(
      xs, wq, 0, nullptr, q16, k16, v16, qsum, ksum);
  k34_flow<<<dim3(cBH, cN / 256), 256, 0, stream>>>(q16, k16, qsum, ksum, si, Sq, Sk);
  k45_kv<<<dim3(cBH, KV_SPLIT), 256, 0, stream>>>(k16, v16, Sq, kvpart, zpart);
  k5r_reduce<<<dim3(cBH, 4), 256, 0, stream>>>(kvpart, zpart, kvm, Zb);
  kvw_build<<<dim3(cBH, 4), 256, 0, stream>>>(kvm, Wproj, Zb, kvw);
  k6c_scaleq<<<dim3(cBH, cN / 256), 256, 0, stream>>>(q16, si, Sk, xq);
  gemm_mfma<1, 4><<<dim3(cM / 128, cHD / 128), 256, 0, stream>>>(
      xq, kvw, cC * cHD, bproj, out, nullptr, nullptr, nullptr, nullptr);
}

// Round 20
// 224.829 us; speedup vs baseline: 1.1790x; 1.1790x over previous
//
#include <hip/hip_runtime.h>
#include <hip/hip_bf16.h>

typedef __attribute__((ext_vector_type(8))) short short8;
typedef __attribute__((ext_vector_type(4))) float f32x4;

constexpr int cB = 4, cN = 8192, cC = 512, cH = 8, cD = 64;
constexpr int cM = cB * cN;        // 32768 tokens
constexpr int cHD = cH * cD;       // 512
constexpr int cBH = cB * cH;       // 32
constexpr float kEPS = 1e-6f;
constexpr int KV_SPLIT = 32;       // k45 split-K slices

// ---- RNE f32 -> bf16 (unbiased) ----
__device__ __forceinline__ ushort rne_bf16(float f) {
  unsigned u = __float_as_uint(f);
  u += 0x7fffu + ((u >> 16) & 1u);
  return (ushort)(u >> 16);
}
__device__ __forceinline__ float b2f(ushort u) {
  return __uint_as_float((unsigned)u << 16);
}

// ---------------- rounder: f32 -> single bf16 (RNE); used for Wqkv and x ----------------
__global__ __launch_bounds__(256) void round_w(const float* __restrict__ src,
    ushort* __restrict__ w, int n4) {
  int i = blockIdx.x * 256 + threadIdx.x;
  if (i >= n4) return;
  float4 v = reinterpret_cast<const float4*>(src)[i];
  ushort4 h;
  h.x = rne_bf16(v.x); h.y = rne_bf16(v.y);
  h.z = rne_bf16(v.z); h.w = rne_bf16(v.w);
  reinterpret_cast<ushort4*>(w)[i] = h;
}

// ---------------- single-bf16 MFMA GEMM: C = A[Mx512] @ W[NCx512]^T ----------------
// r18 BEST-MEASURED CONFIG (228.4 us total; gemm0 112 us) — final consolidation.
// BK=64 single-buffer loop (8 K-steps, 2 barriers/step, 32 MFMA/step).
// ni-inner write-coalesced epilogue (WRITE_SIZE at the 99 MB ideal).
// colsum ALIASED into A-tile LDS (dead after K-loop) -> LDS exactly 32 KB
// -> 5 blocks/CU. Swizzle: stage linear dest + source unit u^=(row&7);
// read unit (hh*4+lg)^(r&7) -> 2-way banks (free). Bijective XCD swizzle.
// EPI=0: epilogue scatters qkv as RNE-bf16 + fused qsum/ksum (f32 pre-round sums).
// EPI=1: epilogue out = acc + bias (f32). bstride = per-b B offset (kvW).
// NOTE (r7 lesson): gemm1 (the d_out writer) reads NOTHING from d_out.
// Schedule scorecard (all refcheck'd): this=112us; BK32=112-121; counted
// vmcnt=119; dbuf=127; 256^2=137; wave-private=144. Local optimum.
template<int EPI, int NY>
__global__ __launch_bounds__(256) void gemm_mfma(
    const ushort* __restrict__ Ab, const ushort* __restrict__ Wb, int bstride,
    const float* __restrict__ bias,
    void* __restrict__ o0v, void* __restrict__ o1v, void* __restrict__ o2v,
    float* __restrict__ qsum, float* __restrict__ ksum) {
  constexpr int NT = cC / 64;                   // 8 K-steps of BK=64
  __shared__ ushort AhS[128 * 64];              // 16 KB (colsum aliases after loop)
  __shared__ ushort BhS[128 * 64];              // 16 KB
  float* colsum = (float*)AhS;                  // alive only after the K-loop
  const int t = threadIdx.x;
  const int wave = t >> 6, lane = t & 63;
  const int wm = wave >> 1, wn = wave & 1;      // 2x2 waves of 64x64
  const int l15 = lane & 15, lg = lane >> 4;

  // ---- XCD-chunked bijective swizzle (nwg % 8 == 0 for both launches) ----
  const int raw = blockIdx.y * gridDim.x + blockIdx.x;
  const int q8 = (int)(gridDim.x * NY) >> 3;
  const int wg2 = (raw & 7) * q8 + (raw >> 3);
  const int rowchunk = wg2 / NY, ycol = wg2 - rowchunk * NY;
  const int row0 = rowchunk * 128, col0 = ycol * 128;
  const size_t wofs = (size_t)(row0 >> 13) * (size_t)bstride;  // per-b B offset

  f32x4 acc[4][4] = {};

  const int lrow = lane >> 3, lunit = lane & 7; // stage: 8 lanes/row x 16B

#define STAGE_T(basep, base0, dst, k0)                                          \
  _Pragma("unroll")                                                             \
  for (int cc = 0; cc < 4; ++cc) {                                              \
    const int row = wave * 32 + cc * 8 + lrow;                                  \
    const int sw = lunit ^ (row & 7);                                           \
    const size_t goff = (size_t)(base0 + row) * cC + (k0) + sw * 8;             \
    __builtin_amdgcn_global_load_lds(                                           \
        (const __attribute__((address_space(1))) void*)(basep + goff),          \
        (__attribute__((address_space(3))) void*)(&dst[(wave * 32 + cc * 8) * 64]), \
        16, 0, 0);                                                              \
  }

  for (int kt = 0; kt < NT; ++kt) {
    STAGE_T(Ab, row0, AhS, kt * 64);
    STAGE_T((Wb + wofs), col0, BhS, kt * 64);
    __syncthreads();
    short8 ah[4][2];
    #pragma unroll
    for (int mi = 0; mi < 4; ++mi) {
      const int r = wm * 64 + mi * 16 + l15;
      #pragma unroll
      for (int hh = 0; hh < 2; ++hh)
        ah[mi][hh] = *reinterpret_cast<const short8*>(
            &AhS[r * 64 + ((hh * 4 + lg) ^ (r & 7)) * 8]);
    }
    #pragma unroll
    for (int ni = 0; ni < 4; ++ni) {
      const int c = wn * 64 + ni * 16 + l15;
      const short8 bh0 = *reinterpret_cast<const short8*>(
          &BhS[c * 64 + ((lg) ^ (c & 7)) * 8]);
      const short8 bh1 = *reinterpret_cast<const short8*>(
          &BhS[c * 64 + ((4 + lg) ^ (c & 7)) * 8]);
      #pragma unroll
      for (int mi = 0; mi < 4; ++mi) {
        acc[mi][ni] = __builtin_amdgcn_mfma_f32_16x16x32_bf16(ah[mi][0], bh0, acc[mi][ni], 0, 0, 0);
        acc[mi][ni] = __builtin_amdgcn_mfma_f32_16x16x32_bf16(ah[mi][1], bh1, acc[mi][ni], 0, 0, 0);
      }
    }
    __syncthreads();
  }
#undef STAGE_T

  // ---- colsum init (aliases A-tile LDS; safe after loop-final barrier) ----
  const bool qk_block = (EPI == 0) && (ycol < 8);
  if (qk_block) {
    if (t < 128) colsum[t] = 0.f;
    __syncthreads();
  }

  // ---- epilogue: C/D map col=lane&15, row=(lane>>4)*4+r; ni-inner stores ----
  float csum[4] = {};
  #pragma unroll
  for (int mi = 0; mi < 4; ++mi) {
    #pragma unroll
    for (int r = 0; r < 4; ++r) {
      const int m = row0 + wm * 64 + mi * 16 + lg * 4 + r;
      #pragma unroll
      for (int ni = 0; ni < 4; ++ni) {
        const int col = col0 + wn * 64 + ni * 16 + l15;
        const float val = acc[mi][ni][r];
        if (EPI == 0) {
          const int which = col >> 9;
          const int c2 = col & 511;
          const int h = c2 >> 6, d = c2 & 63;
          const int bb = m >> 13, n = m & 8191;
          const size_t idx = (((size_t)(bb * cH + h)) * cN + n) * cD + d;
          if (which < 2) {
            const float sv = 1.f / (1.f + __expf(-val));
            if (which == 0) ((ushort*)o0v)[idx] = rne_bf16(sv);
            else            ((ushort*)o1v)[idx] = rne_bf16(sv);
            csum[ni] += sv;
          } else {
            ((ushort*)o2v)[idx] = rne_bf16(val * 0.125f);
          }
        } else {
          ((float*)o0v)[(size_t)m * cC + col] = val + bias[col];
        }
      }
    }
  }
  if (qk_block) {
    #pragma unroll
    for (int ni = 0; ni < 4; ++ni)
      atomicAdd(&colsum[wn * 64 + ni * 16 + l15], csum[ni]);
    __syncthreads();
    if (t < 128) {
      const int col = col0 + t;
      const int c2 = col & 511;
      const int h = c2 >> 6, d = c2 & 63;
      const int bb = row0 >> 13;
      float* tgt = (col < 512) ? qsum : ksum;
      atomicAdd(&tgt[(bb * cH + h) * cD + d], colsum[t]);
    }
  }
}

// ---------------- K34: si, so; accumulate Sq, Sk (bf16 q/k inputs) ----------------
__global__ __launch_bounds__(256) void k34_flow(const ushort* __restrict__ q,
      const ushort* __restrict__ k, const float* __restrict__ qsum,
      const float* __restrict__ ksum, float* __restrict__ si,
      float* __restrict__ Sq, float* __restrict__ Sk) {
  const int bh = blockIdx.x;
  const int n0 = blockIdx.y * 256;
  const int t = threadIdx.x;
  const int wave = t >> 6, lane = t & 63;
  const int g = lane >> 4, j = lane & 15;
  const ushort* qb = q + (size_t)bh * cN * cD;
  const ushort* kb = k + (size_t)bh * cN * cD;
  const float4 ks4 = *(const float4*)&ksum[bh * 64 + j * 4];
  const float4 qs4 = *(const float4*)&qsum[bh * 64 + j * 4];
  const float ksd[4] = {ks4.x + kEPS, ks4.y + kEPS, ks4.z + kEPS, ks4.w + kEPS};
  const float qsd[4] = {qs4.x + kEPS, qs4.y + kEPS, qs4.z + kEPS, qs4.w + kEPS};
  float aSq[4] = {}, aSk[4] = {};
  for (int i = 0; i < 16; ++i) {
    const int n = n0 + wave * 64 + i * 4 + g;
    const ushort4 qu = *(const ushort4*)&qb[(size_t)n * cD + j * 4];
    const ushort4 ku = *(const ushort4*)&kb[(size_t)n * cD + j * 4];
    const float qa[4] = {b2f(qu.x), b2f(qu.y), b2f(qu.z), b2f(qu.w)};
    const float ka[4] = {b2f(ku.x), b2f(ku.y), b2f(ku.z), b2f(ku.w)};
    float t1 = 0.f, t2 = 0.f;
    #pragma unroll
    for (int c = 0; c < 4; ++c) {
      t1 = fmaf(qa[c] + kEPS, ksd[c], t1);
      t2 = fmaf(ka[c] + kEPS, qsd[c], t2);
    }
    #pragma unroll
    for (int off = 1; off < 16; off <<= 1) {
      t1 += __shfl_xor(t1, off);
      t2 += __shfl_xor(t2, off);
    }
    const float si_n = 1.f / (t1 + kEPS);
    const float so_n = 1.f / (t2 + kEPS);
    if (j == 0) si[(size_t)bh * cN + n] = si_n;
    #pragma unroll
    for (int c = 0; c < 4; ++c) {
      aSq[c] = fmaf(qa[c], si_n, aSq[c]);
      aSk[c] = fmaf(ka[c], so_n, aSk[c]);
    }
  }
  #pragma unroll
  for (int c = 0; c < 4; ++c) {
    aSq[c] += __shfl_xor(aSq[c], 16); aSq[c] += __shfl_xor(aSq[c], 32);
    aSk[c] += __shfl_xor(aSk[c], 16); aSk[c] += __shfl_xor(aSk[c], 32);
  }
  __shared__ float sAq[4][64], sAk[4][64];
  if (g == 0) {
    #pragma unroll
    for (int c = 0; c < 4; ++c) { sAq[wave][j * 4 + c] = aSq[c]; sAk[wave][j * 4 + c] = aSk[c]; }
  }
  __syncthreads();
  if (t < 64) {
    atomicAdd(&Sq[bh * 64 + t], sAq[0][t] + sAq[1][t] + sAq[2][t] + sAq[3][t]);
    atomicAdd(&Sk[bh * 64 + t], sAk[0][t] + sAk[1][t] + sAk[2][t] + sAk[3][t]);
  }
}

// ---------------- K45: split-K kv partials (NO atomics), ev inline; bf16 k/v in ----------------
__global__ __launch_bounds__(256) void k45_kv(const ushort* __restrict__ kk_,
      const ushort* __restrict__ vv, const float* __restrict__ Sq,
      float* __restrict__ kvpart, float* __restrict__ zpart) {
  const int bh = blockIdx.x;
  const int y = blockIdx.y;                       // KV_SPLIT slices
  constexpr int ROWS = cN / KV_SPLIT;             // 256
  const int n0 = y * ROWS;
  const int t = threadIdx.x;
  const int d = t & 63, eb = t >> 6;
  const int g = t >> 4, j = t & 15;               // 16 ev-groups of 16 lanes
  const int sr = t >> 4, sc = (t & 15) * 4;       // stage mapping
  const ushort* kb = kk_ + (size_t)bh * cN * cD;
  const ushort* vb = vv + (size_t)bh * cN * cD;
  const float4 sq4 = *(const float4*)&Sq[bh * 64 + j * 4];
  const float SqE[4] = {sq4.x + kEPS, sq4.y + kEPS, sq4.z + kEPS, sq4.w + kEPS};
  __shared__ float ks[32][64];
  __shared__ float vs[32][64];
  __shared__ float evs[32];
  __shared__ float zl[16];
  float acc[16] = {};
  float zacc = 0.f;
  ushort4 pk0 = *(const ushort4*)&kb[(size_t)(n0 + sr) * cD + sc];
  ushort4 pk1 = *(const ushort4*)&kb[(size_t)(n0 + 16 + sr) * cD + sc];
  ushort4 pv0 = *(const ushort4*)&vb[(size_t)(n0 + sr) * cD + sc];
  ushort4 pv1 = *(const ushort4*)&vb[(size_t)(n0 + 16 + sr) * cD + sc];
  for (int c0 = 0; c0 < ROWS; c0 += 32) {
    __syncthreads();
    *(float4*)&ks[sr][sc]      = make_float4(b2f(pk0.x), b2f(pk0.y), b2f(pk0.z), b2f(pk0.w));
    *(float4*)&ks[sr + 16][sc] = make_float4(b2f(pk1.x), b2f(pk1.y), b2f(pk1.z), b2f(pk1.w));
    *(float4*)&vs[sr][sc]      = make_float4(b2f(pv0.x), b2f(pv0.y), b2f(pv0.z), b2f(pv0.w));
    *(float4*)&vs[sr + 16][sc] = make_float4(b2f(pv1.x), b2f(pv1.y), b2f(pv1.z), b2f(pv1.w));
    __syncthreads();
    if (c0 + 32 < ROWS) {
      pk0 = *(const ushort4*)&kb[(size_t)(n0 + c0 + 32 + sr) * cD + sc];
      pk1 = *(const ushort4*)&kb[(size_t)(n0 + c0 + 48 + sr) * cD + sc];
      pv0 = *(const ushort4*)&vb[(size_t)(n0 + c0 + 32 + sr) * cD + sc];
      pv1 = *(const ushort4*)&vb[(size_t)(n0 + c0 + 48 + sr) * cD + sc];
    }
    #pragma unroll
    for (int rr = 0; rr < 2; ++rr) {
      const int r = g * 2 + rr;
      const float4 kk4 = *(const float4*)&ks[r][j * 4];
      float tt = 0.f;
      tt = fmaf(kk4.x + kEPS, SqE[0], tt);
      tt = fmaf(kk4.y + kEPS, SqE[1], tt);
      tt = fmaf(kk4.z + kEPS, SqE[2], tt);
      tt = fmaf(kk4.w + kEPS, SqE[3], tt);
      #pragma unroll
      for (int off = 1; off < 16; off <<= 1) tt += __shfl_xor(tt, off);
      if (j == 0) {
        const float cs = fminf(fmaxf(tt + kEPS, -1.f), 1.f);
        const float e = __expf(cs);
        evs[r] = e;
        zacc += e;
      }
    }
    __syncthreads();
    #pragma unroll
    for (int r = 0; r < 32; ++r) {
      const float kd = ks[r][d] * evs[r];
      #pragma unroll
      for (int j2 = 0; j2 < 16; ++j2)
        acc[j2] = fmaf(kd, vs[r][eb * 16 + j2], acc[j2]);
    }
  }
  if (j == 0) zl[g] = zacc;
  __syncthreads();
  if (t == 0) {
    float z = 0.f;
    #pragma unroll
    for (int i = 0; i < 16; ++i) z += zl[i];
    zpart[y * cBH + bh] = z;
  }
  float* kvb = kvpart + ((size_t)y * cBH + bh) * 4096 + d * 64 + eb * 16;
  #pragma unroll
  for (int j2 = 0; j2 < 16; ++j2) kvb[j2] = acc[j2];
}

// ---------------- K5R: fold split-K partials -> kvm, Zb (deterministic) ----------------
__global__ __launch_bounds__(256) void k5r_reduce(const float* __restrict__ kvpart,
      const float* __restrict__ zpart, float* __restrict__ kvm, float* __restrict__ Zb) {
  const int bh = blockIdx.x;
  const int yq = blockIdx.y;                      // 4 chunks of 1024
  const int t = threadIdx.x;
  for (int i = yq * 1024 + t; i < (yq + 1) * 1024; i += 256) {
    float s = 0.f;
    #pragma unroll
    for (int yy = 0; yy < KV_SPLIT; ++yy)
      s += kvpart[((size_t)yy * cBH + bh) * 4096 + i];
    kvm[(size_t)bh * 4096 + i] = s;
  }
  if (yq == 0 && t == 0) {
    float z = 0.f;
    #pragma unroll
    for (int yy = 0; yy < KV_SPLIT; ++yy) z += zpart[yy * cBH + bh];
    Zb[bh] = z;
  }
}

// ---------------- KVW: kvw[b][c*512 + h*64+d] = RNE( (N/Z)·(kv_bh @ Wproj_h^T)[d,c] ) ----------------
__global__ __launch_bounds__(256) void kvw_build(const float* __restrict__ kvm,
      const float* __restrict__ Wproj, const float* __restrict__ Zb,
      ushort* __restrict__ kvw) {
  const int bh = blockIdx.x;                     // 32
  const int c0 = blockIdx.y * 128;               // 4 c-chunks
  const int b = bh >> 3, h = bh & 7;
  const int t = threadIdx.x;
  __shared__ float kvs[64][64];
  for (int i = t; i < 4096; i += 256)
    kvs[i >> 6][i & 63] = kvm[(size_t)bh * 4096 + i];
  __syncthreads();
  const float zs = (float)cN / Zb[bh];
  const int cl = t & 127, half = t >> 7;         // c-local, d-half
  const int c = c0 + cl;
  float acc[32] = {};
  for (int ec = 0; ec < 64; ec += 8) {
    float w[8];
    #pragma unroll
    for (int e = 0; e < 8; ++e)
      w[e] = Wproj[(size_t)c * cHD + h * 64 + ec + e];
    #pragma unroll
    for (int d = 0; d < 32; ++d)
      #pragma unroll
      for (int e = 0; e < 8; ++e)
        acc[d] = fmaf(kvs[half * 32 + d][ec + e], w[e], acc[d]);
  }
  ushort* dst = kvw + (size_t)b * cC * cHD + (size_t)c * cC + h * 64 + half * 32;
  #pragma unroll
  for (int d = 0; d < 32; ++d) dst[d] = rne_bf16(acc[d] * zs);
}

// ---------------- K6c: A' = RNE_bf16( q · si · sa ), [M][512] token-major; bf16 q in ----------------
__global__ __launch_bounds__(256) void k6c_scaleq(const ushort* __restrict__ q,
      const float* __restrict__ si, const float* __restrict__ Sk,
      ushort* __restrict__ xq) {
  const int bh = blockIdx.x;
  const int b = bh >> 3, head = bh & 7;
  const int n0 = blockIdx.y * 256;
  const int t = threadIdx.x;
  const int wave = t >> 6, lane = t & 63;
  const int g = lane >> 4, j = lane & 15;
  const ushort* qb = q + (size_t)bh * cN * cD;
  const float4 sk4 = *(const float4*)&Sk[bh * 64 + j * 4];
  const float SkE[4] = {sk4.x + kEPS, sk4.y + kEPS, sk4.z + kEPS, sk4.w + kEPS};
  for (int i = 0; i < 16; ++i) {
    const int n = n0 + wave * 64 + i * 4 + g;
    const ushort4 qu = *(const ushort4*)&qb[(size_t)n * cD + j * 4];
    const float q0 = b2f(qu.x), q1 = b2f(qu.y), q2 = b2f(qu.z), q3 = b2f(qu.w);
    float t2 = 0.f;
    t2 = fmaf(q0 + kEPS, SkE[0], t2);
    t2 = fmaf(q1 + kEPS, SkE[1], t2);
    t2 = fmaf(q2 + kEPS, SkE[2], t2);
    t2 = fmaf(q3 + kEPS, SkE[3], t2);
    #pragma unroll
    for (int off = 1; off < 16; off <<= 1) t2 += __shfl_xor(t2, off);
    const float sa_n = 1.f / (1.f + __expf(-(t2 + kEPS)));
    const float s = si[(size_t)bh * cN + n] * sa_n;
    ushort4 hh;
    hh.x = rne_bf16(q0 * s);
    hh.y = rne_bf16(q1 * s);
    hh.z = rne_bf16(q2 * s);
    hh.w = rne_bf16(q3 * s);
    const size_t m = (size_t)b * cN + n;
    *(ushort4*)&xq[m * cC + head * 64 + j * 4] = hh;
  }
}

extern "C" void kernel_launch(void* const* d_in, const int* in_sizes, int n_in,
                              void* d_out, int out_size, void* d_ws, size_t ws_size,
                              hipStream_t stream) {
  (void)in_sizes; (void)n_in; (void)out_size;
  const float* x     = (const float*)d_in[0];
  const float* Wqkv  = (const float*)d_in[1];
  const float* Wproj = (const float*)d_in[2];
  const float* bproj = (const float*)d_in[3];
  float* out = (float*)d_out;
  float* ws  = (float*)d_ws;

  const size_t SLAB = (size_t)cBH * cN * cD;       // 16,777,216 elements
  const size_t OFF_Q   = 0;                        // q bf16
  const size_t OFF_K   = SLAB;                     // k bf16
  const size_t OFF_V   = 2 * SLAB;                 // v bf16 [first half]; xq [second half]
  const size_t OFF_ACC = 3 * SLAB;
  const size_t ACC_FLOATS = 2048 * 4 + 32 + (size_t)cBH * cD * cD;  // 139,296
  const size_t OFF_R   = OFF_ACC + ACC_FLOATS;     // time-shared region
  const size_t R_FLOATS = (size_t)3 * cHD * cC;    // 786,432 floats (r8-proven fit)
  const size_t TOTAL   = OFF_R + R_FLOATS;
  if (ws_size < TOTAL * sizeof(float)) return;

  ushort* q16 = (ushort*)(ws + OFF_Q);             // SLAB ushorts = 32 MB
  ushort* k16 = (ushort*)(ws + OFF_K);
  ushort* v16 = (ushort*)(ws + OFF_V);
  ushort* xq  = (ushort*)(ws + OFF_V + SLAB / 2);  // disjoint second half of v region
  float* ksum = ws + OFF_ACC;
  float* qsum = ksum + 2048;
  float* Sk   = ksum + 4096;
  float* Sq   = ksum + 6144;
  float* Zb   = ksum + 8192;
  float* kvm  = ksum + 8224;

  // region R timeline (786,432 floats):
  //   [0 .. 393216)         wq bf16 (786,432 ushorts)    alive: round_w -> gemm0
  //   [0 .. 262144)         si                            alive: k34 -> k6c (after gemm0)
  //   [262144 .. 786432)    kvw bf16 (1,048,576 ushorts)  alive: kvw_build -> gemm1
  ushort* wq  = (ushort*)(ws + OFF_R);
  float*  si  = ws + OFF_R;
  ushort* kvw = (ushort*)(ws + OFF_R + (size_t)cBH * cN);   // +262144 floats

  // d_out scratch timeline (gemm1 writes ALL of d_out last, reads none of it):
  //   xs bf16 [0 .. 8M floats)       alive: round_w(x) -> gemm0
  //   kvpart  [8M .. 12M floats)     alive: k45 -> k5r
  //   zpart   [12M .. 12M+1K)        alive: k45 -> k5r
  ushort* xs    = (ushort*)out;                          // 16M ushorts = 32 MB
  float* kvpart = out + (size_t)8 * 1024 * 1024;
  float* zpart  = kvpart + (size_t)KV_SPLIT * cBH * 4096;

  hipMemsetAsync(ksum, 0, ACC_FLOATS * sizeof(float), stream);

  round_w<<<(3 * cHD * cC / 4 + 255) / 256, 256, 0, stream>>>(Wqkv, wq, 3 * cHD * cC / 4);
  round_w<<<((size_t)cM * cC / 4 + 255) / 256, 256, 0, stream>>>(x, xs, cM * cC / 4);
  gemm_mfma<0, 12><<<dim3(cM / 128, (3 * cHD) / 128), 256, 0, stream>>>(
      xs, wq, 0, nullptr, q16, k16, v16, qsum, ksum);
  k34_flow<<<dim3(cBH, cN / 256), 256, 0, stream>>>(q16, k16, qsum, ksum, si, Sq, Sk);
  k45_kv<<<dim3(cBH, KV_SPLIT), 256, 0, stream>>>(k16, v16, Sq, kvpart, zpart);
  k5r_reduce<<<dim3(cBH, 4), 256, 0, stream>>>(kvpart, zpart, kvm, Zb);
  kvw_build<<<dim3(cBH, 4), 256, 0, stream>>>(kvm, Wproj, Zb, kvw);
  k6c_scaleq<<<dim3(cBH, cN / 256), 256, 0, stream>>>(q16, si, Sk, xq);
  gemm_mfma<1, 4><<<dim3(cM / 128, cHD / 128), 256, 0, stream>>>(
      xq, kvw, cC * cHD, bproj, out, nullptr, nullptr, nullptr, nullptr);
}